// Round 13
// baseline (3064.888 us; speedup 1.0000x reference)
//
#include <hip/hip_runtime.h>
#include <hip/hip_fp16.h>
#include <math.h>

#define Tn 1024
#define Bn 256
#define Hn 120
#define Ln 4
#define NBC 16                // batch chunks of 16
#define NBCOL 16              // cols per chunk
#define NBLK (Ln*NBC)         // 64 blocks
#define THR 576               // 8 compute waves + 1 DMA wave
#define Dd 16                 // ring depth
#define PADI 32
#define KPh 520               // col stride u16: 260 dwords, %32==4 -> 2-way (free)
#define ENT 2048              // ring entry u16: 8w*16col*4quad*4m

typedef _Float16 f16x8 __attribute__((ext_vector_type(8)));
typedef float    f32x4 __attribute__((ext_vector_type(4)));
typedef unsigned int u32x2 __attribute__((ext_vector_type(2)));
typedef unsigned short ushort_t;

template<int N> struct IC { static constexpr int value = N; };

// R26 = R23 compute structure + DMA-wave specialization (R25's sc0-only
// same-XCD scope was INCOHERENT -> reverted to proven system-scope).
// Waves 0-7: exactly R23's GEMM/cell/reg-ring-store/vmcnt(1)/BAR -- but
// ZERO loads and ZERO spins. Wave 8 owns the handshake: prodUp/consDn
// spins, ring loads issued a FULL step before staging (L(t+1) issued at
// step t-1 -> ~1.5us cover >> MALL latency), LDS staging, cons posts.
// consDn guard runs one step early (covers S(t'+1..t'+4)); the barrier
// orders it ahead of compute stores -> race-free. x2 unroll only in the
// DMA branch (static parity regs, rule #20). 1 block/CU, 9 waves.
__device__ ushort_t g_ring[(size_t)3 * Dd * NBC * ENT];
__device__ int g_prod[3 * NBC * PADI];
__device__ int g_cons[Ln * NBC * PADI];
__device__ int g_abort;

__global__ __launch_bounds__(256) void init_kernel() {
    int idx = threadIdx.x;
    if (idx < 3 * NBC)  g_prod[idx * PADI] = -1;
    if (idx < Ln * NBC) g_cons[idx * PADI] = -1;
    if (idx == 0)       g_abort = 0;
}

#if __has_builtin(__builtin_amdgcn_exp2f)
__device__ __forceinline__ float hw_exp2(float x) { return __builtin_amdgcn_exp2f(x); }
#else
__device__ __forceinline__ float hw_exp2(float x) { return exp2f(x); }
#endif
#if __has_builtin(__builtin_amdgcn_rcpf)
__device__ __forceinline__ float hw_rcp(float x) { return __builtin_amdgcn_rcpf(x); }
#else
__device__ __forceinline__ float hw_rcp(float x) { return 1.0f / x; }
#endif
#define LOG2E_F 1.44269504f

__device__ __forceinline__ float sigm(float v) {
    return hw_rcp(1.0f + hw_exp2(-LOG2E_F * v));
}
__device__ __forceinline__ float tanh_fast(float v) {
    return 1.0f - 2.0f * hw_rcp(1.0f + hw_exp2(2.0f * LOG2E_F * v));
}

// raw barrier: waits LDS ops only; vmem stays in flight across it.
#define BAR_LGKM() asm volatile("s_waitcnt lgkmcnt(0)\ns_barrier" ::: "memory")

__device__ __forceinline__ void spin_wait(int* p, int tgt, int& dead, int& pc) {
    if (dead || pc >= tgt) return;
    int guard = 0, v;
    while ((v = __hip_atomic_load(p, __ATOMIC_RELAXED,
                                  __HIP_MEMORY_SCOPE_SYSTEM)) < tgt) {
        __builtin_amdgcn_s_sleep(1);
        if ((++guard & 127) == 0) {
            if (__hip_atomic_load(&g_abort, __ATOMIC_RELAXED,
                                  __HIP_MEMORY_SCOPE_SYSTEM)) { dead = 1; return; }
            if (guard > 60000) { atomicExch(&g_abort, 1); dead = 1; return; }
        }
    }
    pc = v;
}

__device__ __forceinline__ void post_flag(int* p, int v) {
    __hip_atomic_store(p, v, __ATOMIC_RELAXED, __HIP_MEMORY_SCOPE_SYSTEM);
}

// LDS per col (u16): [0..119] h par0, [120..127] pad/x, [128..255] bh par0,
// [256..375] h par1 (+pad), [384..511] bh par1.
__global__ __launch_bounds__(THR, 1) void lstm_kernel(
    const float* __restrict__ x,    const float* __restrict__ h0,
    const float* __restrict__ c0,   const float* __restrict__ Wih0,
    const float* __restrict__ Wih,  const float* __restrict__ Whh,
    const float* __restrict__ bih,  const float* __restrict__ bhh,
    const float* __restrict__ Wlin, const float* __restrict__ blin,
    float* __restrict__ out)
{
    __shared__ _Float16 hxT[NBCOL * KPh];   // 16.6 KB

    const int bx   = blockIdx.x;
    const int l    = bx >> 4;
    const int bc   = bx & 15;
    const int tid  = threadIdx.x;
    const int w    = tid >> 6;
    const int lane = tid & 63;
    const int quad = lane >> 4;
    const int l16  = lane & 15;
    const int bg0  = bc * NBCOL;

    const float* WhhL = Whh + (size_t)l * 4 * Hn * Hn;
    const float* WihL = (l > 0) ? Wih + (size_t)(l - 1) * 4 * Hn * Hn : Whh;
    ushort_t* ringP = g_ring + (size_t)l * Dd * NBC * ENT;              // l<3
    const ushort_t* ringC =
        g_ring + (size_t)(l > 0 ? l - 1 : 0) * Dd * NBC * ENT;
    int* prodUp = &g_prod[(l > 0 ? ((l - 1) * NBC + bc) : 0) * PADI];
    int* prodMe = &g_prod[(l < 3 ? (l * NBC + bc) : 0) * PADI];
    int* consDn = &g_cons[(l < 3 ? ((l + 1) * NBC + bc) : 0) * PADI];
    int* consMe = &g_cons[(l * NBC + bc) * PADI];

    // ---- shared prologue: zero LDS; h0 -> h par1; x(0) -> par1 pad slot
    for (int q2 = tid; q2 < NBCOL * KPh; q2 += THR) hxT[q2] = (_Float16)0.f;
    __syncthreads();
    for (int q2 = tid; q2 < NBCOL * Hn; q2 += THR) {
        int col = q2 / Hn, cell = q2 % Hn;
        hxT[col * KPh + 256 + cell] = (_Float16)h0[(l * Bn + bg0 + col) * Hn + cell];
    }
    if (l == 0 && tid < NBCOL)
        hxT[tid * KPh + 256 + 120] = (_Float16)x[bg0 + tid];
    __syncthreads();

    if (w < 8) {
        // ================= COMPUTE WAVES (R23 structure, no vmem loads) ==
        const int mtn = (w < 6) ? 4 : 3;
        const int mt0 = (w < 6) ? 4 * w : 24 + 3 * (w - 6);

        // A-fragments; k<120: Whh(cell=k); k==120 (l0): Wih0; k>=128: bh
        // slot s=k-128 -> cell invpi(s) of Wih.
        f16x8 a[4][8];
        #pragma unroll
        for (int m = 0; m < 4; ++m) {
            int rp = (mt0 + m) * 16 + l16;
            int cell = rp >> 2, gate = rp & 3;
            int orow = gate * Hn + cell;
            #pragma unroll
            for (int kt = 0; kt < 8; ++kt) {
                f16x8 av;
                #pragma unroll
                for (int j = 0; j < 8; ++j) {
                    int k = kt * 32 + quad * 8 + j;
                    float v = 0.f;
                    if (m < mtn) {
                        if (k < Hn)          v = WhhL[orow * Hn + k];
                        else if (l == 0)     { if (k == 120) v = Wih0[orow]; }
                        else if (k >= 128) {
                            int s = k - 128, w2 = s >> 4, r = s & 15;
                            int q2 = r >> 2, m2 = r & 3;
                            int mtn2 = (w2 < 6) ? 4 : 3;
                            int mt02 = (w2 < 6) ? 4 * w2 : 24 + 3 * (w2 - 6);
                            if (m2 < mtn2)
                                v = WihL[orow * Hn + (mt02 + m2) * 4 + q2];
                        }
                    }
                    av[j] = (_Float16)v;
                }
                a[m][kt] = av;
            }
        }

        float bias_g[4][4];
        float cst[4];
        #pragma unroll
        for (int m = 0; m < 4; ++m) {
            int cell = (mt0 + m) * 4 + quad;
            #pragma unroll
            for (int g = 0; g < 4; ++g)
                bias_g[m][g] = (m < mtn)
                    ? bih[l * 4 * Hn + g * Hn + cell] + bhh[l * 4 * Hn + g * Hn + cell]
                    : 0.f;
            cst[m] = (m < mtn) ? c0[(l * Bn + bg0 + l16) * Hn + cell] : 0.f;
        }

        const int oc_col = tid >> 3, oc_j = tid & 7;  // l3 out (tid<128)
        float wl[15];
        if (l == 3) {
            #pragma unroll
            for (int c2 = 0; c2 < 15; ++c2) wl[c2] = Wlin[oc_j * 15 + c2];
        }

        if (l > 0) __syncthreads();   // pairs with DMA prologue staging sync

        auto run = [&](auto ktlc) {
            constexpr int KTL = decltype(ktlc)::value;
            for (int t = 0; t < Tn; ++t) {
                const int q  = t & 1;
                const int hR = (q ^ 1) << 8;
                const int hW = q << 8;

                f32x4 acc[4];
                #pragma unroll
                for (int m = 0; m < 4; ++m) {
                    f32x4 z; z[0] = bias_g[m][0]; z[1] = bias_g[m][1];
                    z[2] = bias_g[m][2]; z[3] = bias_g[m][3];
                    acc[m] = z;
                }
                unsigned short hb[4] = {0, 0, 0, 0};

                #pragma unroll
                for (int half = 0; half < 2; ++half) {
                    const int M0 = half * 2;
                    #pragma unroll
                    for (int kt = 0; kt < KTL; ++kt) {
                        const int e0 = kt * 32 + quad * 8;
                        const int ao = e0 + ((kt < 4) ? hR : (q << 8));
                        f16x8 bfr = *(const f16x8*)&hxT[l16 * KPh + ao];
                        #pragma unroll
                        for (int m = M0; m < M0 + 2; ++m)
                            if (m < mtn)
                                acc[m] = __builtin_amdgcn_mfma_f32_16x16x32_f16(
                                    a[m][kt], bfr, acc[m], 0, 0, 0);
                    }
                    #pragma unroll
                    for (int m = M0; m < M0 + 2; ++m) {
                        if (m >= mtn) continue;
                        int cell = (mt0 + m) * 4 + quad;
                        float ig = sigm(acc[m][0]);
                        float fg = sigm(acc[m][1]);
                        float gg = tanh_fast(acc[m][2]);
                        float og = sigm(acc[m][3]);
                        float cn = fmaf(fg, cst[m], ig * gg);
                        cst[m] = cn;
                        float hn = og * tanh_fast(cn);
                        _Float16 hh = (_Float16)hn;
                        hxT[l16 * KPh + hW + cell] = hh;
                        hb[m] = __builtin_bit_cast(unsigned short, hh);
                    }
                }

                if (l < 3) {
                    u32x2 sv;
                    sv[0] = (unsigned)hb[0] | ((unsigned)hb[1] << 16);
                    sv[1] = (unsigned)hb[2] | ((unsigned)hb[3] << 16);
                    ushort_t* p0 = ringP + (size_t)((t & (Dd - 1)) * NBC + bc) * ENT
                                 + w * 256 + l16 * 16 + quad * 4;
                    asm volatile("global_store_dwordx2 %0, %1, off sc0 sc1"
                                 :: "v"(p0), "v"(sv) : "memory");
                    asm volatile("s_waitcnt vmcnt(1)" ::: "memory"); // retire S(t-1)
                }

                BAR_LGKM();   // h(t) + DMA-staged(t+1) visible

                if (l == 3 && tid < NBCOL * 8) {
                    float pout = 0.f;
                    const _Float16* hrow = &hxT[oc_col * KPh + hW + oc_j * 15];
                    #pragma unroll
                    for (int c2 = 0; c2 < 15; ++c2)
                        pout = fmaf(wl[c2], (float)hrow[c2], pout);
                    pout += __shfl_down(pout, 4, 8);
                    pout += __shfl_down(pout, 2, 8);
                    pout += __shfl_down(pout, 1, 8);
                    if (oc_j == 0) out[t * Bn + bg0 + oc_col] = pout + blin[0];
                }
                if ((t & 3) == 3 && l < 3 && tid == 0)
                    post_flag(prodMe, t - 1);    // S(t-1) drained by all waves
            }
        };
        if (l == 0) run(IC<4>{});
        else        run(IC<8>{});
    } else {
        // ================= DMA WAVE (w == 8) ============================
        int dead = 0, pcb = -0x40000000, pca = -0x40000000;
        // staging offsets: virtual idx v=i*64+lane reads ring u16 [v*4,v*4+4)
        int sgo[8];
        #pragma unroll
        for (int i = 0; i < 8; ++i) {
            int v = i * 64 + lane;
            int col = (v >> 2) & 15, w2 = v >> 6, q2 = v & 3;
            sgo[i] = col * KPh + 128 + w2 * 16 + q2 * 4;
        }
        u32x2 ldA[8], ldB[8];
        #pragma unroll
        for (int i = 0; i < 8; ++i) { ldA[i] = (u32x2){0,0}; ldB[i] = (u32x2){0,0}; }
        float xrA = 0.f, xrB = 0.f;

        if (l > 0) {
            spin_wait(prodUp, 1, dead, pcb);
            const ushort_t* b0 = ringC + (size_t)(0 * NBC + bc) * ENT;
            const ushort_t* b1 = ringC + (size_t)(1 * NBC + bc) * ENT;
            u32x2 v0[8];
            #pragma unroll
            for (int i = 0; i < 8; ++i) {
                const ushort_t* p = b0 + (i * 64 + lane) * 4;
                asm volatile("global_load_dwordx2 %0, %1, off sc0 sc1"
                             : "=v"(v0[i]) : "v"(p));
            }
            #pragma unroll
            for (int i = 0; i < 8; ++i) {
                const ushort_t* p = b1 + (i * 64 + lane) * 4;
                asm volatile("global_load_dwordx2 %0, %1, off sc0 sc1"
                             : "=v"(ldA[i]) : "v"(p));
            }
            asm volatile("s_waitcnt vmcnt(0)" ::: "memory");
            __builtin_amdgcn_sched_barrier(0);
            #pragma unroll
            for (int i = 0; i < 8; ++i)
                *(u32x2*)&hxT[sgo[i]] = v0[i];   // bh(0) -> parity0
            __syncthreads();                      // pairs with compute's sync
            if (lane == 0) post_flag(consMe, 1);
        } else {
            if (lane < NBCOL) xrA = x[Bn + bg0 + lane];   // x(1) seed
        }

        auto dstep = [&](int t, auto par, u32x2 (&ldS)[8], u32x2 (&ldI)[8],
                         float& xrS, float& xrI) {
            constexpr int P = decltype(par)::value;
            if ((t & 3) == 0) {
                if (l > 0) {
                    int tgt = (t + 5 < Tn) ? t + 5 : Tn - 1;
                    spin_wait(prodUp, tgt, dead, pcb);
                }
                if (l < 3 && t >= 12)
                    spin_wait(consDn, t - 12, dead, pca);
            }
            // issue L(t+2) / x(t+2)
            if (l > 0 && (t + 2) < Tn) {
                const ushort_t* base =
                    ringC + (size_t)(((t + 2) & (Dd - 1)) * NBC + bc) * ENT;
                #pragma unroll
                for (int i = 0; i < 8; ++i) {
                    const ushort_t* p = base + (i * 64 + lane) * 4;
                    asm volatile("global_load_dwordx2 %0, %1, off sc0 sc1"
                                 : "=v"(ldI[i]) : "v"(p));
                }
            }
            if (l == 0 && (t + 2) < Tn && lane < NBCOL) {
                const float* px = x + (size_t)(t + 2) * Bn + bg0 + lane;
                asm volatile("global_load_dword %0, %1, off"
                             : "=v"(xrI) : "v"(px));
            }
            // retire the stage buffer (issued a full step ago)
            if (l > 0) {
                if ((t + 2) < Tn) asm volatile("s_waitcnt vmcnt(8)" ::: "memory");
                else              asm volatile("s_waitcnt vmcnt(0)" ::: "memory");
            } else {
                if ((t + 2) < Tn) asm volatile("s_waitcnt vmcnt(1)" ::: "memory");
                else              asm volatile("s_waitcnt vmcnt(0)" ::: "memory");
            }
            __builtin_amdgcn_sched_barrier(0);
            // stage bh(t+1)/x(t+1) into parity P^1 regions
            if (l > 0 && (t + 1) < Tn) {
                #pragma unroll
                for (int i = 0; i < 8; ++i)
                    *(u32x2*)&hxT[sgo[i] + ((P ^ 1) << 8)] = ldS[i];
            }
            if (l == 0 && (t + 1) < Tn && lane < NBCOL)
                hxT[lane * KPh + (P << 8) + 120] = (_Float16)xrS;

            BAR_LGKM();

            if ((t & 3) == 3 && l > 0 && lane == 0)
                post_flag(consMe, t + 1);         // staged thru t+1
        };

        for (int t = 0; t < Tn; t += 2) {
            dstep(t,     IC<0>{}, ldA, ldB, xrA, xrB);
            dstep(t + 1, IC<1>{}, ldB, ldA, xrB, xrA);
        }
    }

    // ---- epilogue (all waves): retire final ring stores, post last prod
    if (l < 3) {
        asm volatile("s_waitcnt vmcnt(0)" ::: "memory");
        __syncthreads();
        if (tid == 0) post_flag(prodMe, Tn - 1);
    }
}

extern "C" void kernel_launch(void* const* d_in, const int* in_sizes, int n_in,
                              void* d_out, int out_size, void* d_ws, size_t ws_size,
                              hipStream_t stream) {
    const float* x    = (const float*)d_in[0];
    const float* h0   = (const float*)d_in[1];
    const float* c0   = (const float*)d_in[2];
    const float* Wih0 = (const float*)d_in[3];
    const float* Wih  = (const float*)d_in[4];
    const float* Whh  = (const float*)d_in[5];
    const float* bih  = (const float*)d_in[6];
    const float* bhh  = (const float*)d_in[7];
    const float* Wlin = (const float*)d_in[8];
    const float* blin = (const float*)d_in[9];
    float* out = (float*)d_out;

    hipLaunchKernelGGL(init_kernel, dim3(1), dim3(256), 0, stream);
    hipLaunchKernelGGL(lstm_kernel, dim3(NBLK), dim3(THR), 0, stream,
                       x, h0, c0, Wih0, Wih, Whh, bih, bhh, Wlin, blin, out);
}

// Round 14
// 1531.063 us; speedup vs baseline: 2.0018x; 2.0018x over previous
//
#include <hip/hip_runtime.h>
#include <hip/hip_fp16.h>
#include <math.h>

#define Tn 1024
#define Bn 256
#define Hn 120
#define Ln 4
#define NBC 16                // batch chunks of 16
#define NBCOL 16              // cols per chunk
#define NBLK (Ln*NBC)         // 64 blocks
#define THR 512               // 8 waves
#define Dd 16                 // ring depth
#define PADI 32
#define KPh 520               // col stride u16: 260 dwords, %32==4 -> 2-way (free)
#define ENT 2048              // ring entry u16: 8w*16col*4quad*4m

typedef _Float16 f16x8 __attribute__((ext_vector_type(8)));
typedef float    f32x4 __attribute__((ext_vector_type(4)));
typedef unsigned int u32x2 __attribute__((ext_vector_type(2)));
typedef unsigned short ushort_t;

template<int N> struct IC { static constexpr int value = N; };

// R27 = R23 verbatim (verified 1534us, absmax 4.88e-4). Reverts R26:
// the DMA-wave branch dropped VGPR 128->84 = A-fragments demoted to
// scratch (rule #20 class), 2x regression. R24 (depth-2 prefetch) and
// R25 (same-XCD sc0 scope, INCOHERENT) also failed their tripwires.
// R23 structure: single lgkm barrier/step, reg-sourced ring stores with
// inverse-permuted A-gather, entry-issued ring loads overlapping
// GEMM+cell, counted vmcnt(1) drain, batch-4 system-scope flags,
// h/bh parity LDS regions.
__device__ ushort_t g_ring[(size_t)3 * Dd * NBC * ENT];
__device__ int g_prod[3 * NBC * PADI];
__device__ int g_cons[Ln * NBC * PADI];
__device__ int g_abort;

__global__ __launch_bounds__(256) void init_kernel() {
    int idx = threadIdx.x;
    if (idx < 3 * NBC)  g_prod[idx * PADI] = -1;
    if (idx < Ln * NBC) g_cons[idx * PADI] = -1;
    if (idx == 0)       g_abort = 0;
}

#if __has_builtin(__builtin_amdgcn_exp2f)
__device__ __forceinline__ float hw_exp2(float x) { return __builtin_amdgcn_exp2f(x); }
#else
__device__ __forceinline__ float hw_exp2(float x) { return exp2f(x); }
#endif
#if __has_builtin(__builtin_amdgcn_rcpf)
__device__ __forceinline__ float hw_rcp(float x) { return __builtin_amdgcn_rcpf(x); }
#else
__device__ __forceinline__ float hw_rcp(float x) { return 1.0f / x; }
#endif
#define LOG2E_F 1.44269504f

__device__ __forceinline__ float sigm(float v) {
    return hw_rcp(1.0f + hw_exp2(-LOG2E_F * v));
}
__device__ __forceinline__ float tanh_fast(float v) {
    return 1.0f - 2.0f * hw_rcp(1.0f + hw_exp2(2.0f * LOG2E_F * v));
}

// raw barrier: waits LDS ops only; vmem stays in flight across it.
#define BAR_LGKM() asm volatile("s_waitcnt lgkmcnt(0)\ns_barrier" ::: "memory")

__device__ __forceinline__ void spin_wait(int* p, int tgt, int& dead, int& pc) {
    if (dead || pc >= tgt) return;
    int guard = 0, v;
    while ((v = __hip_atomic_load(p, __ATOMIC_RELAXED,
                                  __HIP_MEMORY_SCOPE_SYSTEM)) < tgt) {
        __builtin_amdgcn_s_sleep(1);
        if ((++guard & 127) == 0) {
            if (__hip_atomic_load(&g_abort, __ATOMIC_RELAXED,
                                  __HIP_MEMORY_SCOPE_SYSTEM)) { dead = 1; return; }
            if (guard > 60000) { atomicExch(&g_abort, 1); dead = 1; return; }
        }
    }
    pc = v;
}

__device__ __forceinline__ void post_flag(int* p, int v) {
    __hip_atomic_store(p, v, __ATOMIC_RELAXED, __HIP_MEMORY_SCOPE_SYSTEM);
}

__global__ __launch_bounds__(THR, 2) void lstm_kernel(
    const float* __restrict__ x,    const float* __restrict__ h0,
    const float* __restrict__ c0,   const float* __restrict__ Wih0,
    const float* __restrict__ Wih,  const float* __restrict__ Whh,
    const float* __restrict__ bih,  const float* __restrict__ bhh,
    const float* __restrict__ Wlin, const float* __restrict__ blin,
    float* __restrict__ out)
{
    __shared__ _Float16 hxT[NBCOL * KPh];   // 16.6 KB

    const int bx   = blockIdx.x;
    const int l    = bx >> 4;
    const int bc   = bx & 15;
    const int tid  = threadIdx.x;
    const int w    = tid >> 6;
    const int lane = tid & 63;
    const int quad = lane >> 4;
    const int l16  = lane & 15;
    const int bg0  = bc * NBCOL;
    const int mtn  = (w < 6) ? 4 : 3;
    const int mt0  = (w < 6) ? 4 * w : 24 + 3 * (w - 6);
    int dead = 0, pcb = -0x40000000, pca = -0x40000000;

    const float* WhhL = Whh + (size_t)l * 4 * Hn * Hn;
    const float* WihL = (l > 0) ? Wih + (size_t)(l - 1) * 4 * Hn * Hn : Whh;
    ushort_t* ringP = g_ring + (size_t)l * Dd * NBC * ENT;              // l<3
    const ushort_t* ringC =
        g_ring + (size_t)(l > 0 ? l - 1 : 0) * Dd * NBC * ENT;
    int* prodUp = &g_prod[(l > 0 ? ((l - 1) * NBC + bc) : 0) * PADI];
    int* prodMe = &g_prod[(l < 3 ? (l * NBC + bc) : 0) * PADI];
    int* consDn = &g_cons[(l < 3 ? ((l + 1) * NBC + bc) : 0) * PADI];
    int* consMe = &g_cons[(l * NBC + bc) * PADI];

    // ---- persistent A-fragments; k<120: Whh(cell=k); 120..127: pad
    // (l0: k==120 -> Wih0); k>=128: bh slot s=k-128, cell via invpi(s).
    f16x8 a[4][8];
    #pragma unroll
    for (int m = 0; m < 4; ++m) {
        int rp = (mt0 + m) * 16 + l16;          // permuted row 0..479
        int cell = rp >> 2, gate = rp & 3;
        int orow = gate * Hn + cell;
        #pragma unroll
        for (int kt = 0; kt < 8; ++kt) {
            f16x8 av;
            #pragma unroll
            for (int j = 0; j < 8; ++j) {
                int k = kt * 32 + quad * 8 + j;
                float v = 0.f;
                if (m < mtn) {
                    if (k < Hn)          v = WhhL[orow * Hn + k];
                    else if (l == 0)     { if (k == 120) v = Wih0[orow]; }
                    else if (k >= 128) {
                        int s = k - 128, w2 = s >> 4, r = s & 15;
                        int q2 = r >> 2, m2 = r & 3;
                        int mtn2 = (w2 < 6) ? 4 : 3;
                        int mt02 = (w2 < 6) ? 4 * w2 : 24 + 3 * (w2 - 6);
                        if (m2 < mtn2)
                            v = WihL[orow * Hn + (mt02 + m2) * 4 + q2];
                    }
                }
                av[j] = (_Float16)v;
            }
            a[m][kt] = av;
        }
    }

    float bias_g[4][4];
    float cst[4];
    #pragma unroll
    for (int m = 0; m < 4; ++m) {
        int cell = (mt0 + m) * 4 + quad;
        #pragma unroll
        for (int g = 0; g < 4; ++g)
            bias_g[m][g] = (m < mtn)
                ? bih[l * 4 * Hn + g * Hn + cell] + bhh[l * 4 * Hn + g * Hn + cell]
                : 0.f;
        cst[m] = (m < mtn) ? c0[(l * Bn + bg0 + l16) * Hn + cell] : 0.f;
    }

    // consumer staging indices: ring u16 i=tid*4 -> (w2,col,q2,m0..3)
    const int sg_col = (tid >> 2) & 15;
    const int sg_w   = tid >> 6;
    const int sg_q   = tid & 3;
    const int sg_lds = sg_col * KPh + 128 + sg_w * 16 + sg_q * 4; // + parity*256

    const int oc_col = tid >> 3, oc_j = tid & 7;  // l3 out (tid<128)
    float wl[15];
    if (l == 3) {
        #pragma unroll
        for (int c2 = 0; c2 < 15; ++c2) wl[c2] = Wlin[oc_j * 15 + c2];
    }

    // init: zero everything once, then h0 -> pong h region (256+)
    for (int q2 = tid; q2 < NBCOL * KPh; q2 += THR) hxT[q2] = (_Float16)0.f;
    __syncthreads();
    for (int q2 = tid; q2 < NBCOL * Hn; q2 += THR) {
        int col = q2 / Hn, cell = q2 % Hn;
        hxT[col * KPh + 256 + cell] = (_Float16)h0[(l * Bn + bg0 + col) * Hn + cell];
    }
    __syncthreads();

    // ---- prologue: stage bh(0) into bh-ping (128) / x(0) into h-pong pad
    if (l > 0) {
        spin_wait(prodUp, 0, dead, pcb);
        u32x2 v0 = {0, 0};
        const ushort_t* p = ringC + (size_t)(0 * NBC + bc) * ENT + tid * 4;
        asm volatile("global_load_dwordx2 %0, %1, off sc0 sc1"
                     : "=v"(v0) : "v"(p));
        asm volatile("s_waitcnt vmcnt(0)" ::: "memory");
        *(u32x2*)&hxT[sg_lds] = v0;              // parity 0 region
        __syncthreads();
        if (tid == 96) post_flag(consMe, 0);
    } else {
        if (tid < NBCOL) hxT[tid * KPh + 256 + 120] = (_Float16)x[bg0 + tid];
        __syncthreads();
    }

    auto run = [&](auto ktlc) {
        constexpr int KTL = decltype(ktlc)::value;
        for (int t = 0; t < Tn; ++t) {
            const int slotW = t & (Dd - 1);
            const int slotR = (t + 1) & (Dd - 1);
            const int q  = t & 1;
            const int hR = (q ^ 1) << 8;          // h(t-1) region
            const int hW = q << 8;                // h(t) region

            if ((t & 3) == 0) {
                if (l > 0) {
                    int tgt = (t + 4 < Tn) ? t + 4 : Tn - 1;
                    spin_wait(prodUp, tgt, dead, pcb);
                }
                if (l < 3 && t >= 16)
                    spin_wait(consDn, t - 13, dead, pca);
            }

            // ---- entry: issue next-step vmem (flies under GEMM+cell)
            u32x2 ld = {0, 0};
            float xr = 0.f;
            if (l > 0 && (t + 1) < Tn) {
                const ushort_t* p = ringC + (size_t)(slotR * NBC + bc) * ENT + tid * 4;
                asm volatile("global_load_dwordx2 %0, %1, off sc0 sc1"
                             : "=v"(ld) : "v"(p));
            }
            if (l == 0 && (t + 1) < Tn && tid < NBCOL)
                xr = x[(t + 1) * Bn + bg0 + tid];

            // ---- GEMM + cell halves; pack h bits for reg-sourced ring store
            f32x4 acc[4];
            #pragma unroll
            for (int m = 0; m < 4; ++m) {
                f32x4 z; z[0] = bias_g[m][0]; z[1] = bias_g[m][1];
                z[2] = bias_g[m][2]; z[3] = bias_g[m][3];
                acc[m] = z;
            }
            unsigned short hb[4] = {0, 0, 0, 0};

            #pragma unroll
            for (int half = 0; half < 2; ++half) {
                const int M0 = half * 2;
                #pragma unroll
                for (int kt = 0; kt < KTL; ++kt) {
                    const int e0 = kt * 32 + quad * 8;
                    const int ao = e0 + ((kt < 4) ? hR : (q << 8));
                    f16x8 bfr = *(const f16x8*)&hxT[l16 * KPh + ao];
                    #pragma unroll
                    for (int m = M0; m < M0 + 2; ++m)
                        if (m < mtn)
                            acc[m] = __builtin_amdgcn_mfma_f32_16x16x32_f16(
                                a[m][kt], bfr, acc[m], 0, 0, 0);
                }
                #pragma unroll
                for (int m = M0; m < M0 + 2; ++m) {
                    if (m >= mtn) continue;
                    int cell = (mt0 + m) * 4 + quad;
                    float ig = sigm(acc[m][0]);
                    float fg = sigm(acc[m][1]);
                    float gg = tanh_fast(acc[m][2]);
                    float og = sigm(acc[m][3]);
                    float cn = fmaf(fg, cst[m], ig * gg);
                    cst[m] = cn;
                    float hn = og * tanh_fast(cn);
                    _Float16 hh = (_Float16)hn;
                    hxT[l16 * KPh + hW + cell] = hh;
                    hb[m] = __builtin_bit_cast(unsigned short, hh);
                }
            }

            // ---- ring store S(t) from regs (producer order; pads are 0)
            if (l < 3) {
                u32x2 sv;
                sv[0] = (unsigned)hb[0] | ((unsigned)hb[1] << 16);
                sv[1] = (unsigned)hb[2] | ((unsigned)hb[3] << 16);
                ushort_t* p0 = ringP + (size_t)(slotW * NBC + bc) * ENT
                             + w * 256 + l16 * 16 + quad * 4;
                asm volatile("global_store_dwordx2 %0, %1, off sc0 sc1"
                             :: "v"(p0), "v"(sv) : "memory");
            }

            // ---- counted drain: retire store(t-1) + entry load, keep S(t)
            if (l < 3) { asm volatile("s_waitcnt vmcnt(1)" ::: "memory"); }
            else       { asm volatile("s_waitcnt vmcnt(0)" ::: "memory"); }
            __builtin_amdgcn_sched_barrier(0);

            // ---- stage bh(t+1)/x(t+1) into the OTHER parity (no reader now)
            if (l > 0 && (t + 1) < Tn)
                *(u32x2*)&hxT[sg_lds + ((q ^ 1) << 8)] = ld;
            if (l == 0 && (t + 1) < Tn && tid < NBCOL)
                hxT[tid * KPh + hW + 120] = (_Float16)xr;

            BAR_LGKM();   // single barrier: h(t) + staged(t+1) visible

            if (l == 3 && tid < NBCOL * 8) {
                float pout = 0.f;
                const _Float16* hrow = &hxT[oc_col * KPh + hW + oc_j * 15];
                #pragma unroll
                for (int c2 = 0; c2 < 15; ++c2)
                    pout = fmaf(wl[c2], (float)hrow[c2], pout);
                pout += __shfl_down(pout, 4, 8);
                pout += __shfl_down(pout, 2, 8);
                pout += __shfl_down(pout, 1, 8);
                if (oc_j == 0) out[t * Bn + bg0 + oc_col] = pout + blin[0];
            }

            if ((t & 3) == 3) {
                if (l < 3 && tid == 0)  post_flag(prodMe, t - 1);
                if (l > 0 && tid == 96) post_flag(consMe, t + 1);
            }
        }
    };
    if (l == 0) run(IC<4>{});
    else        run(IC<8>{});

    // ---- epilogue: retire final ring stores, post last prod
    if (l < 3) {
        asm volatile("s_waitcnt vmcnt(0)" ::: "memory");
        __syncthreads();
        if (tid == 0) post_flag(prodMe, Tn - 1);
    }
}

extern "C" void kernel_launch(void* const* d_in, const int* in_sizes, int n_in,
                              void* d_out, int out_size, void* d_ws, size_t ws_size,
                              hipStream_t stream) {
    const float* x    = (const float*)d_in[0];
    const float* h0   = (const float*)d_in[1];
    const float* c0   = (const float*)d_in[2];
    const float* Wih0 = (const float*)d_in[3];
    const float* Wih  = (const float*)d_in[4];
    const float* Whh  = (const float*)d_in[5];
    const float* bih  = (const float*)d_in[6];
    const float* bhh  = (const float*)d_in[7];
    const float* Wlin = (const float*)d_in[8];
    const float* blin = (const float*)d_in[9];
    float* out = (float*)d_out;

    hipLaunchKernelGGL(init_kernel, dim3(1), dim3(256), 0, stream);
    hipLaunchKernelGGL(lstm_kernel, dim3(NBLK), dim3(THR), 0, stream,
                       x, h0, c0, Wih0, Wih, Whh, bih, bhh, Wlin, blin, out);
}